// Round 9
// baseline (263.274 us; speedup 1.0000x reference)
//
#include <hip/hip_runtime.h>
#include <hip/hip_cooperative_groups.h>

namespace cg = cooperative_groups;

#define T_DIM 512
#define B_DIM 8192
#define SLT   16                 // timesteps per slab
#define NSLAB (T_DIM / SLT)      // 32 slabs
#define GC    1024               // columns per block
#define NCG   (B_DIM / GC)       // 8 column groups
#define NTH   1024
#define NBLK  (NSLAB * NCG)      // 256 blocks = 1/CU
#define GAMMA 0.99f

// Workspace float-offset layout (cooperative path): S | M | Cin | partials
#define WS_S    0
#define WS_M    (NSLAB * B_DIM)        // 262144
#define WS_CIN  (2 * NSLAB * B_DIM)    // 524288
#define WS_PART (3 * NSLAB * B_DIM)    // 786432
#define WS_NEED_BYTES ((size_t)(WS_PART + 2 * NBLK) * sizeof(float))

// Rounds 0-8: six structurally different kernels (regs/LDS/DMA staging,
// occ 33-66%, scalar & wide loads) ALL deliver 2.7-3.0 TB/s logical.
// Invariant: blocks own full-T column panels -> 64-128B per array per
// DRAM row per block, ~1500-3000 concurrent fine-grained strided streams
// -> DRAM row-activate on nearly every access (~33% HBM efficiency =
// the observed 2 TB/s). Fix: tile 16t x 1024cols so each block reads
// 4-8KB CONTIGUOUS per array per row. T split across blocks => grid-wide
// scan => cooperative launch, rs kept in LDS across the sync.
__global__ __launch_bounds__(NTH)
void vtrace_coop(const float* __restrict__ prob,
                 const float* __restrict__ aprob,
                 const float* __restrict__ v,
                 const float* __restrict__ nv,
                 const float* __restrict__ rw,
                 const int* __restrict__ act,
                 const int* __restrict__ dnn,
                 float* __restrict__ ws) {
    __shared__ unsigned int rs[SLT][NTH];   // ratio w/ done sign (64 KB)
    __shared__ float red[32];

    cg::grid_group grid = cg::this_grid();

    const int tid = threadIdx.x;
    const int bid = blockIdx.x;
    const int s   = bid >> 3;               // slab       0..31
    const int g   = bid & (NCG - 1);        // col group  0..7
    const int col = g * GC + tid;
    const int t0  = s * SLT;

    const float2* __restrict__ prob2  = (const float2*)prob;
    const float2* __restrict__ aprob2 = (const float2*)aprob;

    // ---- phase 1: own tile, contiguous 4-8KB row chunks -----------------
    float S = 0.0f, M = 1.0f;
#pragma unroll
    for (int i = SLT - 1; i >= 0; --i) {
        const size_t idx = (size_t)(t0 + i) * B_DIM + col;
        const float2 pr = prob2[idx];
        const float2 qr = aprob2[idx];
        const float  vv = v[idx];
        const float  rr = rw[idx];
        const int    a  = act[idx];
        const int    d  = dnn[idx];

        const float pa    = a ? pr.y : pr.x;
        const float qa    = a ? qr.y : qr.x;
        const float ratio = (pa * (qr.x + qr.y)) / ((pr.x + pr.y) * qa);
        const float rho   = fminf(ratio, 1.0f);
        const float m     = d ? 0.0f : GAMMA * rho;
        const float p     = rho * (rr - vv);

        rs[i][tid] = __float_as_uint(ratio) | ((unsigned)d << 31);
        // compose f_t(x) = (vv+p) + m*x in front of running composite
        S = (vv + p) + m * S;
        M = m * M;
    }
    ws[WS_S + s * B_DIM + col] = S;
    ws[WS_M + s * B_DIM + col] = M;

    grid.sync();

    // ---- phase 2: cross-slab scan, 8 blocks x 1024 cols -----------------
    if (bid < NCG) {
        const int c2 = bid * NTH + tid;
        float carry = nv[(size_t)(T_DIM - 1) * B_DIM + c2];
#pragma unroll
        for (int ss = NSLAB - 1; ss >= 0; --ss) {
            ws[WS_CIN + ss * B_DIM + c2] = carry;   // carry entering slab ss
            carry = fmaf(ws[WS_M + ss * B_DIM + c2], carry,
                         ws[WS_S + ss * B_DIM + c2]);
        }
    }

    grid.sync();

    // ---- phase 3: replay own tile (v,rw L2-hot; rs from LDS) ------------
    float carry  = ws[WS_CIN + s * B_DIM + col];
    float critic = 0.0f, msum = 0.0f;
#pragma unroll
    for (int i = SLT - 1; i >= 0; --i) {
        const size_t idx = (size_t)(t0 + i) * B_DIM + col;
        const float vv = v[idx];
        const float rr = rw[idx];
        const unsigned u = rs[i][tid];

        const float r_  = __uint_as_float(u & 0x7fffffffu);
        const float m   = ((int)u < 0) ? 0.0f : GAMMA * fminf(r_, 1.0f);
        const float p   = fminf(r_, 1.0f) * (rr - vv);  // bit-identical to ph1
        const float t_  = m * carry;
        const float adv = p + t_;                 // == -(v - vtrace)
        carry = (vv + p) + t_;                    // vtrace_t
        critic = fmaf(adv, adv, critic);
        msum += (adv >= 0.0f) ? fminf(r_, 1.2f) * adv
                              : fmaxf(r_, 0.8f) * adv;
    }

    // ---- block reduction: wave64 shuffle then cross-wave via LDS --------
#pragma unroll
    for (int off = 32; off > 0; off >>= 1) {
        critic += __shfl_down(critic, off, 64);
        msum   += __shfl_down(msum, off, 64);
    }
    const int wave = tid >> 6;
    if ((tid & 63) == 0) { red[wave] = critic; red[16 + wave] = msum; }
    __syncthreads();
    if (tid == 0) {
        float cs = 0.0f, ms = 0.0f;
#pragma unroll
        for (int w = 0; w < 16; ++w) { cs += red[w]; ms += red[16 + w]; }
        ws[WS_PART + bid]        = cs;   // critic partial
        ws[WS_PART + NBLK + bid] = ms;   // min-surrogate partial
    }
}

// ---------- fallback (r3 kernel, known-good ~50us) if ws too small -------
#define GB_FB 16
#define NC_FB 64
#define LC_FB 8
__global__ __launch_bounds__(1024)
void vtrace_fb(const float* __restrict__ prob, const float* __restrict__ aprob,
               const float* __restrict__ v, const float* __restrict__ nv,
               const float* __restrict__ rw, const int* __restrict__ act,
               const int* __restrict__ dnn, float* __restrict__ partials) {
    __shared__ float Sc[NC_FB][GB_FB];
    __shared__ float Mc[NC_FB][GB_FB];
    __shared__ float Cin[NC_FB][GB_FB];
    __shared__ float red[32];
    const int tid = threadIdx.x;
    const int bl  = tid & (GB_FB - 1);
    const int c   = tid >> 4;
    const int b   = blockIdx.x * GB_FB + bl;
    const float2* __restrict__ prob2  = (const float2*)prob;
    const float2* __restrict__ aprob2 = (const float2*)aprob;
    const size_t base = (size_t)(c * LC_FB) * B_DIM + b;
    float S = 0.0f, M = 1.0f;
    float r0,r1,r2,r3,r4,r5,r6,r7, p0,p1,p2,p3,p4,p5,p6,p7,
          w0,w1,w2,w3,w4,w5,w6,w7;
#define STEPA(i)                                                            \
    {                                                                       \
        const size_t idx = base + (size_t)(i) * B_DIM;                      \
        float2 pr = prob2[idx]; float2 qr = aprob2[idx];                    \
        float vvi = v[idx]; float rr = rw[idx];                             \
        int a = act[idx]; int d = dnn[idx];                                 \
        float pa = a ? pr.y : pr.x; float qa = a ? qr.y : qr.x;             \
        float ratio = (pa * (qr.x + qr.y)) / ((pr.x + pr.y) * qa);          \
        float rho = fminf(ratio, 1.0f);                                     \
        float m = d ? 0.0f : GAMMA * rho;                                   \
        float p = rho * (rr - vvi);                                         \
        r##i = __uint_as_float(__float_as_uint(ratio) |                     \
                               ((unsigned)d << 31));                        \
        p##i = p; w##i = vvi;                                               \
        S = (vvi + p) + m * S; M = m * M;                                   \
    }
    STEPA(7) STEPA(6) STEPA(5) STEPA(4) STEPA(3) STEPA(2) STEPA(1) STEPA(0)
#undef STEPA
    Sc[c][bl] = S; Mc[c][bl] = M;
    __syncthreads();
    if (tid < GB_FB) {
        float carry = nv[(size_t)(T_DIM - 1) * B_DIM + blockIdx.x * GB_FB + tid];
#pragma unroll 8
        for (int cc = NC_FB - 1; cc >= 0; --cc) {
            Cin[cc][tid] = carry;
            carry = fmaf(Mc[cc][tid], carry, Sc[cc][tid]);
        }
    }
    __syncthreads();
    float carry = Cin[c][bl];
    float critic = 0.0f, msum = 0.0f;
#define STEPB(i)                                                            \
    {                                                                       \
        const unsigned u = __float_as_uint(r##i);                           \
        const float r_ = __uint_as_float(u & 0x7fffffffu);                  \
        const float m = ((int)u < 0) ? 0.0f : GAMMA * fminf(r_, 1.0f);      \
        const float adv = fmaf(m, carry, p##i);                             \
        carry = w##i + adv;                                                 \
        critic = fmaf(adv, adv, critic);                                    \
        msum += (adv >= 0.0f) ? fminf(r_, 1.2f) * adv                       \
                              : fmaxf(r_, 0.8f) * adv;                      \
    }
    STEPB(7) STEPB(6) STEPB(5) STEPB(4) STEPB(3) STEPB(2) STEPB(1) STEPB(0)
#undef STEPB
#pragma unroll
    for (int off = 32; off > 0; off >>= 1) {
        critic += __shfl_down(critic, off, 64);
        msum   += __shfl_down(msum, off, 64);
    }
    const int wave = tid >> 6;
    if ((tid & 63) == 0) { red[wave] = critic; red[16 + wave] = msum; }
    __syncthreads();
    if (tid == 0) {
        float cs = 0.0f, ms = 0.0f;
#pragma unroll
        for (int w = 0; w < 16; ++w) { cs += red[w]; ms += red[16 + w]; }
        partials[blockIdx.x]       = cs;
        partials[512 + blockIdx.x] = ms;
    }
}

// n = number of partials per quantity (256 coop / 512 fallback)
__global__ void vtrace_final(const float* __restrict__ partials, int n,
                             float* __restrict__ out) {
    __shared__ float red[16];
    const int tid = threadIdx.x;            // 512 threads
    float cs = (tid < n) ? partials[tid] : 0.0f;
    float ms = (tid < n) ? partials[n + tid] : 0.0f;
#pragma unroll
    for (int off = 32; off > 0; off >>= 1) {
        cs += __shfl_down(cs, off, 64);
        ms += __shfl_down(ms, off, 64);
    }
    const int wave = tid >> 6;
    if ((tid & 63) == 0) { red[wave] = cs; red[8 + wave] = ms; }
    __syncthreads();
    if (tid == 0) {
        float c = 0.0f, m = 0.0f;
#pragma unroll
        for (int w = 0; w < 8; ++w) { c += red[w]; m += red[8 + w]; }
        const float invN = 1.0f / (float)((size_t)T_DIM * B_DIM); // exact pow2
        // total = actor + critic = -mean(min(surr)) + 0.5*mean(adv^2)
        out[0] = 0.5f * c * invN - m * invN;
    }
}

extern "C" void kernel_launch(void* const* d_in, const int* in_sizes, int n_in,
                              void* d_out, int out_size, void* d_ws, size_t ws_size,
                              hipStream_t stream) {
    const float* prob  = (const float*)d_in[0];
    const float* aprob = (const float*)d_in[1];
    const float* v     = (const float*)d_in[2];
    const float* nv    = (const float*)d_in[3];
    const float* rw    = (const float*)d_in[4];
    const int*   act   = (const int*)d_in[5];
    const int*   dnn   = (const int*)d_in[6];
    float* ws  = (float*)d_ws;
    float* out = (float*)d_out;

    if (ws_size >= WS_NEED_BYTES) {
        void* args[] = {(void*)&prob, (void*)&aprob, (void*)&v, (void*)&nv,
                        (void*)&rw, (void*)&act, (void*)&dnn, (void*)&ws};
        hipLaunchCooperativeKernel((void*)vtrace_coop, dim3(NBLK), dim3(NTH),
                                   args, 0, stream);
        vtrace_final<<<1, 512, 0, stream>>>(ws + WS_PART, NBLK, out);
    } else {
        vtrace_fb<<<B_DIM / GB_FB, 1024, 0, stream>>>(prob, aprob, v, nv, rw,
                                                      act, dnn, ws);
        vtrace_final<<<1, 512, 0, stream>>>(ws, 512, out);
    }
}

// Round 10
// 188.135 us; speedup vs baseline: 1.3994x; 1.3994x over previous
//
#include <hip/hip_runtime.h>

#define T_DIM 512
#define B_DIM 8192
#define SLT   8                  // timesteps per slab
#define NSLAB (T_DIM / SLT)      // 64 slabs
#define GC    1024               // columns per block
#define NCG   (B_DIM / GC)       // 8 column groups
#define NTH   1024
#define NBLK  (NSLAB * NCG)      // 512 blocks (2/CU)
#define GAMMA 0.99f

// Workspace float-offset layout (split path): rs | S | M | Cin | partials
#define WS_RS   0
#define WS_S    (T_DIM * B_DIM)                  // 4194304
#define WS_M    (WS_S + NSLAB * B_DIM)
#define WS_CIN  (WS_M + NSLAB * B_DIM)
#define WS_PART (WS_CIN + NSLAB * B_DIM)
#define WS_NEED_BYTES ((size_t)(WS_PART + 2 * NBLK) * sizeof(float))

// Rounds 0-8: six single-kernel structures (regs/LDS/DMA staging, occ
// 33-66%, scalar & wide loads) all deliver 2.7-3.0 TB/s logical. The
// invariant: blocks own full-T column panels -> only 64-128B contiguous
// per array per row per block. Round 9 tested contiguous 16tx1024col
// tiles via cooperative launch: grid.sync() itself cost ~60us (118us
// kernel) -> structure rejected, theory still unmeasured. This round:
// SAME tiling, but kernel boundaries as the grid sync. Cross-phase
// ratio state goes through ws (16MB write + read ~ 5-10us, vs 60us of
// grid.sync). Fallback to the known-good r3 kernel if ws too small.

// ---- k1: per-tile ratio + slab affine composition (contiguous reads) ----
__global__ __launch_bounds__(NTH)
void vtrace_p1(const float* __restrict__ prob,
               const float* __restrict__ aprob,
               const float* __restrict__ v,
               const float* __restrict__ rw,
               const int* __restrict__ act,
               const int* __restrict__ dnn,
               float* __restrict__ ws) {
    const int tid = threadIdx.x;
    const int bid = blockIdx.x;
    const int s   = bid >> 3;               // slab       0..63
    const int g   = bid & (NCG - 1);        // col group  0..7
    const int col = g * GC + tid;
    const int t0  = s * SLT;

    const float2* __restrict__ prob2  = (const float2*)prob;
    const float2* __restrict__ aprob2 = (const float2*)aprob;
    unsigned int* __restrict__ wsu = (unsigned int*)ws;

    float S = 0.0f, M = 1.0f;
#pragma unroll
    for (int i = SLT - 1; i >= 0; --i) {
        const size_t idx = (size_t)(t0 + i) * B_DIM + col;
        const float2 pr = prob2[idx];
        const float2 qr = aprob2[idx];
        const float  vv = v[idx];
        const float  rr = rw[idx];
        const int    a  = act[idx];
        const int    d  = dnn[idx];

        const float pa    = a ? pr.y : pr.x;
        const float qa    = a ? qr.y : qr.x;
        const float ratio = (pa * (qr.x + qr.y)) / ((pr.x + pr.y) * qa);
        const float rho   = fminf(ratio, 1.0f);
        const float m     = d ? 0.0f : GAMMA * rho;
        const float p     = rho * (rr - vv);

        wsu[WS_RS + idx] = __float_as_uint(ratio) | ((unsigned)d << 31);
        // compose f_t(x) = (vv+p) + m*x in front of running composite
        S = (vv + p) + m * S;
        M = m * M;
    }
    ws[WS_S + s * B_DIM + col] = S;
    ws[WS_M + s * B_DIM + col] = M;
}

// ---- k2: cross-slab scan per column (loads carry-independent) -----------
__global__ __launch_bounds__(NTH)
void vtrace_scan(const float* __restrict__ nv, float* __restrict__ ws) {
    const int col = blockIdx.x * NTH + threadIdx.x;   // 8 blocks -> 8192 cols
    float carry = nv[(size_t)(T_DIM - 1) * B_DIM + col];
#pragma unroll 8
    for (int ss = NSLAB - 1; ss >= 0; --ss) {
        ws[WS_CIN + ss * B_DIM + col] = carry;        // carry entering slab ss
        carry = fmaf(ws[WS_M + ss * B_DIM + col], carry,
                     ws[WS_S + ss * B_DIM + col]);
    }
}

// ---- k3: replay tiles with true carries; accumulate losses --------------
__global__ __launch_bounds__(NTH)
void vtrace_p3(const float* __restrict__ v,
               const float* __restrict__ rw,
               float* __restrict__ ws) {
    __shared__ float red[32];
    const int tid = threadIdx.x;
    const int bid = blockIdx.x;
    const int s   = bid >> 3;
    const int g   = bid & (NCG - 1);
    const int col = g * GC + tid;
    const int t0  = s * SLT;

    const unsigned int* __restrict__ wsu = (const unsigned int*)ws;

    float carry  = ws[WS_CIN + s * B_DIM + col];
    float critic = 0.0f, msum = 0.0f;
#pragma unroll
    for (int i = SLT - 1; i >= 0; --i) {
        const size_t idx = (size_t)(t0 + i) * B_DIM + col;
        const float vv = v[idx];
        const float rr = rw[idx];
        const unsigned u = wsu[WS_RS + idx];

        const float r_  = __uint_as_float(u & 0x7fffffffu);
        const float m   = ((int)u < 0) ? 0.0f : GAMMA * fminf(r_, 1.0f);
        const float p   = fminf(r_, 1.0f) * (rr - vv);  // bit-identical to k1
        const float t_  = m * carry;
        const float adv = p + t_;                 // == -(v - vtrace)
        carry = (vv + p) + t_;                    // vtrace_t
        critic = fmaf(adv, adv, critic);
        msum += (adv >= 0.0f) ? fminf(r_, 1.2f) * adv
                              : fmaxf(r_, 0.8f) * adv;
    }

#pragma unroll
    for (int off = 32; off > 0; off >>= 1) {
        critic += __shfl_down(critic, off, 64);
        msum   += __shfl_down(msum, off, 64);
    }
    const int wave = tid >> 6;
    if ((tid & 63) == 0) { red[wave] = critic; red[16 + wave] = msum; }
    __syncthreads();
    if (tid == 0) {
        float cs = 0.0f, ms = 0.0f;
#pragma unroll
        for (int w = 0; w < 16; ++w) { cs += red[w]; ms += red[16 + w]; }
        ws[WS_PART + bid]        = cs;   // critic partial
        ws[WS_PART + NBLK + bid] = ms;   // min-surrogate partial
    }
}

// ---------- fallback (r3 kernel, known-good ~50us) if ws too small -------
#define GB_FB 16
#define NC_FB 64
#define LC_FB 8
__global__ __launch_bounds__(1024)
void vtrace_fb(const float* __restrict__ prob, const float* __restrict__ aprob,
               const float* __restrict__ v, const float* __restrict__ nv,
               const float* __restrict__ rw, const int* __restrict__ act,
               const int* __restrict__ dnn, float* __restrict__ partials) {
    __shared__ float Sc[NC_FB][GB_FB];
    __shared__ float Mc[NC_FB][GB_FB];
    __shared__ float Cin[NC_FB][GB_FB];
    __shared__ float red[32];
    const int tid = threadIdx.x;
    const int bl  = tid & (GB_FB - 1);
    const int c   = tid >> 4;
    const int b   = blockIdx.x * GB_FB + bl;
    const float2* __restrict__ prob2  = (const float2*)prob;
    const float2* __restrict__ aprob2 = (const float2*)aprob;
    const size_t base = (size_t)(c * LC_FB) * B_DIM + b;
    float S = 0.0f, M = 1.0f;
    float r0,r1,r2,r3,r4,r5,r6,r7, p0,p1,p2,p3,p4,p5,p6,p7,
          w0,w1,w2,w3,w4,w5,w6,w7;
#define STEPA(i)                                                            \
    {                                                                       \
        const size_t idx = base + (size_t)(i) * B_DIM;                      \
        float2 pr = prob2[idx]; float2 qr = aprob2[idx];                    \
        float vvi = v[idx]; float rr = rw[idx];                             \
        int a = act[idx]; int d = dnn[idx];                                 \
        float pa = a ? pr.y : pr.x; float qa = a ? qr.y : qr.x;             \
        float ratio = (pa * (qr.x + qr.y)) / ((pr.x + pr.y) * qa);          \
        float rho = fminf(ratio, 1.0f);                                     \
        float m = d ? 0.0f : GAMMA * rho;                                   \
        float p = rho * (rr - vvi);                                         \
        r##i = __uint_as_float(__float_as_uint(ratio) |                     \
                               ((unsigned)d << 31));                        \
        p##i = p; w##i = vvi;                                               \
        S = (vvi + p) + m * S; M = m * M;                                   \
    }
    STEPA(7) STEPA(6) STEPA(5) STEPA(4) STEPA(3) STEPA(2) STEPA(1) STEPA(0)
#undef STEPA
    Sc[c][bl] = S; Mc[c][bl] = M;
    __syncthreads();
    if (tid < GB_FB) {
        float carry = nv[(size_t)(T_DIM - 1) * B_DIM + blockIdx.x * GB_FB + tid];
#pragma unroll 8
        for (int cc = NC_FB - 1; cc >= 0; --cc) {
            Cin[cc][tid] = carry;
            carry = fmaf(Mc[cc][tid], carry, Sc[cc][tid]);
        }
    }
    __syncthreads();
    float carry = Cin[c][bl];
    float critic = 0.0f, msum = 0.0f;
#define STEPB(i)                                                            \
    {                                                                       \
        const unsigned u = __float_as_uint(r##i);                           \
        const float r_ = __uint_as_float(u & 0x7fffffffu);                  \
        const float m = ((int)u < 0) ? 0.0f : GAMMA * fminf(r_, 1.0f);      \
        const float adv = fmaf(m, carry, p##i);                             \
        carry = w##i + adv;                                                 \
        critic = fmaf(adv, adv, critic);                                    \
        msum += (adv >= 0.0f) ? fminf(r_, 1.2f) * adv                       \
                              : fmaxf(r_, 0.8f) * adv;                      \
    }
    STEPB(7) STEPB(6) STEPB(5) STEPB(4) STEPB(3) STEPB(2) STEPB(1) STEPB(0)
#undef STEPB
#pragma unroll
    for (int off = 32; off > 0; off >>= 1) {
        critic += __shfl_down(critic, off, 64);
        msum   += __shfl_down(msum, off, 64);
    }
    const int wave = tid >> 6;
    if ((tid & 63) == 0) { red[wave] = critic; red[16 + wave] = msum; }
    __syncthreads();
    if (tid == 0) {
        float cs = 0.0f, ms = 0.0f;
#pragma unroll
        for (int w = 0; w < 16; ++w) { cs += red[w]; ms += red[16 + w]; }
        partials[blockIdx.x]       = cs;
        partials[512 + blockIdx.x] = ms;
    }
}

// n = number of partials per quantity (512 both paths)
__global__ void vtrace_final(const float* __restrict__ partials, int n,
                             float* __restrict__ out) {
    __shared__ float red[16];
    const int tid = threadIdx.x;            // 512 threads
    float cs = (tid < n) ? partials[tid] : 0.0f;
    float ms = (tid < n) ? partials[n + tid] : 0.0f;
#pragma unroll
    for (int off = 32; off > 0; off >>= 1) {
        cs += __shfl_down(cs, off, 64);
        ms += __shfl_down(ms, off, 64);
    }
    const int wave = tid >> 6;
    if ((tid & 63) == 0) { red[wave] = cs; red[8 + wave] = ms; }
    __syncthreads();
    if (tid == 0) {
        float c = 0.0f, m = 0.0f;
#pragma unroll
        for (int w = 0; w < 8; ++w) { c += red[w]; m += red[8 + w]; }
        const float invN = 1.0f / (float)((size_t)T_DIM * B_DIM); // exact pow2
        // total = actor + critic = -mean(min(surr)) + 0.5*mean(adv^2)
        out[0] = 0.5f * c * invN - m * invN;
    }
}

extern "C" void kernel_launch(void* const* d_in, const int* in_sizes, int n_in,
                              void* d_out, int out_size, void* d_ws, size_t ws_size,
                              hipStream_t stream) {
    const float* prob  = (const float*)d_in[0];
    const float* aprob = (const float*)d_in[1];
    const float* v     = (const float*)d_in[2];
    const float* nv    = (const float*)d_in[3];
    const float* rw    = (const float*)d_in[4];
    const int*   act   = (const int*)d_in[5];
    const int*   dnn   = (const int*)d_in[6];
    float* ws  = (float*)d_ws;
    float* out = (float*)d_out;

    if (ws_size >= WS_NEED_BYTES) {
        vtrace_p1<<<NBLK, NTH, 0, stream>>>(prob, aprob, v, rw, act, dnn, ws);
        vtrace_scan<<<NCG, NTH, 0, stream>>>(nv, ws);
        vtrace_p3<<<NBLK, NTH, 0, stream>>>(v, rw, ws);
        vtrace_final<<<1, 512, 0, stream>>>(ws + WS_PART, NBLK, out);
    } else {
        vtrace_fb<<<B_DIM / GB_FB, 1024, 0, stream>>>(prob, aprob, v, nv, rw,
                                                      act, dnn, ws);
        vtrace_final<<<1, 512, 0, stream>>>(ws, 512, out);
    }
}